// Round 6
// baseline (7605.243 us; speedup 1.0000x reference)
//
#include <hip/hip_runtime.h>

// PyramidSampler: B=4 clouds of P=8192 pts, D=512 feats, scales (1.0, 0.5, 0.25).
// Scale 0.25's FPS indices are an exact prefix of scale 0.5's -> one 4096-step
// FPS per batch.
//
// R5: wave-level prune gate on top of R4. R4 analysis: per-step cost 4330 cyc,
// ~half VALU issue; even fully-pruned waves paid ~170 instr/step (group bounds
// + 6 DPP stages + tree). Now each wave has a setup-computed bbox over its
// 1024 contiguous Morton points and a cached wave-reduced key (lane 63 regs);
// if the wave-level bound proves no dist in the region changes, the wave skips
// bounds+update+DPP entirely (uniform branch) and just rewrites its cached
// slot. The global-max point's wave always has lb2w=0 < its max dist, so the
// winner can never be stale. Exact math preserved: no fma, (dx^2+dy^2)+dz^2
// left fold, min-update, ties -> smallest original index (max lo1 = 8192-o).

constexpr int kB   = 4;
constexpr int kP   = 8192;
constexpr int kD   = 512;
constexpr int kN1  = 4096;              // int(P*0.5)
constexpr int kN2  = 2048;              // int(P*0.25)
constexpr int kS   = kP + kN1 + kN2;    // 14336 rows per batch
constexpr int kT   = 512;               // 8 waves
constexpr int kW   = kT / 64;           // 8
constexpr int kPts = kP / kT;           // 16 points per thread
constexpr int kG   = 2;                 // sub-buckets per thread
constexpr int kGp  = kPts / kG;         // 8 points per sub-bucket

typedef unsigned long long u64;
typedef unsigned u32;

template <int CTRL>
__device__ __forceinline__ u32 dpp1(u32 v) {
  return (u32)__builtin_amdgcn_update_dpp((int)v, (int)v, CTRL, 0xF, 0xF, false);
}

// combined argmax key: (dist f32, lo1 u32 tie-break, coords as bits)
__device__ __forceinline__ void keymax(float& d, u32& l, u32& x, u32& y, u32& z,
                                       float od, u32 ol, u32 ox, u32 oy, u32 oz) {
  bool t = (od > d) || (od == d && ol > l);
  d = t ? od : d; l = t ? ol : l;
  x = t ? ox : x; y = t ? oy : y; z = t ? oz : z;
}

// one DPP butterfly/broadcast stage (old=own so non-receiving lanes no-op);
// after all 6 stages the wave-global max lands in lanes 48..63.
#define DPP_STAGE(CTRL)                                                     \
  {                                                                         \
    u32 pd = dpp1<CTRL>(__float_as_uint(kd));                               \
    u32 pl = dpp1<CTRL>(kl);                                                \
    u32 qx = dpp1<CTRL>(kx);                                                \
    u32 qy = dpp1<CTRL>(ky);                                                \
    u32 qz = dpp1<CTRL>(kz);                                                \
    keymax(kd, kl, kx, ky, kz, __uint_as_float(pd), pl, qx, qy, qz);        \
  }

#define DPP_REDUCE6()                                                       \
  DPP_STAGE(0xB1);  /* quad_perm xor1 */                                    \
  DPP_STAGE(0x4E);  /* quad_perm xor2 */                                    \
  DPP_STAGE(0x141); /* row_half_mirror */                                   \
  DPP_STAGE(0x140); /* row_mirror */                                        \
  DPP_STAGE(0x142); /* row_bcast15 */                                       \
  DPP_STAGE(0x143); /* row_bcast31 */

__global__ __launch_bounds__(kT, 2)
void fps_kernel(const float* __restrict__ pos, int* __restrict__ idx_out) {
  const int b    = blockIdx.x;
  const int tid  = threadIdx.x;
  const int wave = tid >> 6;
  const int lane = tid & 63;
  const float* pb = pos + (size_t)b * kP * 3;
  int* idx = idx_out + b * kN1;

  __shared__ __attribute__((aligned(16))) float lds_pos[kP * 3];  // 96 KB (setup only)
  __shared__ u32 lds_key[kP];                                     // 32 KB (setup only)
  __shared__ float lds_bb[kW][6];
  __shared__ __attribute__((aligned(16))) u32 wslot[2][kW][8];    // [par][wave][d,lo1,x,y,z,..]
  __shared__ float lds_c0[3];

  // ---- 1) stage pos into LDS (orig order, coalesced float4) ----
  {
    const float4* src = reinterpret_cast<const float4*>(pb);
    float4* dst = reinterpret_cast<float4*>(lds_pos);
#pragma unroll
    for (int i = 0; i < (kP * 3 / 4) / kT; ++i)        // 12 iters
      dst[tid + i * kT] = src[tid + i * kT];
  }
  __syncthreads();

  // ---- 2) cloud bbox (block reduce; setup-only) ----
  float mn0 = 1e30f, mn1 = 1e30f, mn2 = 1e30f;
  float mx0 = -1e30f, mx1 = -1e30f, mx2 = -1e30f;
  for (int i = tid; i < kP; i += kT) {
    float x = lds_pos[3 * i], y = lds_pos[3 * i + 1], z = lds_pos[3 * i + 2];
    mn0 = fminf(mn0, x); mx0 = fmaxf(mx0, x);
    mn1 = fminf(mn1, y); mx1 = fmaxf(mx1, y);
    mn2 = fminf(mn2, z); mx2 = fmaxf(mx2, z);
  }
#pragma unroll
  for (int m = 32; m >= 1; m >>= 1) {
    mn0 = fminf(mn0, __shfl_xor(mn0, m, 64)); mx0 = fmaxf(mx0, __shfl_xor(mx0, m, 64));
    mn1 = fminf(mn1, __shfl_xor(mn1, m, 64)); mx1 = fmaxf(mx1, __shfl_xor(mx1, m, 64));
    mn2 = fminf(mn2, __shfl_xor(mn2, m, 64)); mx2 = fmaxf(mx2, __shfl_xor(mx2, m, 64));
  }
  if (lane == 0) {
    lds_bb[wave][0] = mn0; lds_bb[wave][1] = mn1; lds_bb[wave][2] = mn2;
    lds_bb[wave][3] = mx0; lds_bb[wave][4] = mx1; lds_bb[wave][5] = mx2;
  }
  __syncthreads();
#pragma unroll
  for (int w = 0; w < kW; ++w) {
    mn0 = fminf(mn0, lds_bb[w][0]); mn1 = fminf(mn1, lds_bb[w][1]); mn2 = fminf(mn2, lds_bb[w][2]);
    mx0 = fmaxf(mx0, lds_bb[w][3]); mx1 = fmaxf(mx1, lds_bb[w][4]); mx2 = fmaxf(mx2, lds_bb[w][5]);
  }

  // ---- 3) Morton keys: 18-bit code << 13 | orig idx ----
  {
    const float i0 = 63.0f / fmaxf(mx0 - mn0, 1e-20f);
    const float i1 = 63.0f / fmaxf(mx1 - mn1, 1e-20f);
    const float i2 = 63.0f / fmaxf(mx2 - mn2, 1e-20f);
    for (int i = tid; i < kP; i += kT) {
      int qx = (int)((lds_pos[3 * i]     - mn0) * i0);
      int qy = (int)((lds_pos[3 * i + 1] - mn1) * i1);
      int qz = (int)((lds_pos[3 * i + 2] - mn2) * i2);
      qx = min(max(qx, 0), 63); qy = min(max(qy, 0), 63); qz = min(max(qz, 0), 63);
      u32 code = 0;
#pragma unroll
      for (int t = 0; t < 6; ++t)
        code |= (((u32)(qx >> t) & 1u) << (3 * t)) |
                (((u32)(qy >> t) & 1u) << (3 * t + 1)) |
                (((u32)(qz >> t) & 1u) << (3 * t + 2));
      lds_key[i] = (code << 13) | (u32)i;
    }
  }
  __syncthreads();

  // ---- 4) bitonic sort of 8192 u32 keys (unique: idx in low bits) ----
  for (int kk = 2; kk <= kP; kk <<= 1) {
    for (int j = kk >> 1; j > 0; j >>= 1) {
      const int mask = j - 1;
#pragma unroll
      for (int it = 0; it < (kP / 2) / kT; ++it) {     // 8 iters
        int i = tid + it * kT;
        int a = ((i & ~mask) << 1) | (i & mask);
        int c = a | j;
        u32 x = lds_key[a], y = lds_key[c];
        bool up = ((a & kk) == 0);
        if ((x > y) == up) { lds_key[a] = y; lds_key[c] = x; }
      }
      __syncthreads();
    }
  }

  // ---- 5) gather 16 pts/thread into registers (sorted order) ----
  float px[kPts], py[kPts], pz[kPts], dist_[kPts];
  u32 lo1_[kPts];                       // 8192 - orig_idx (unique, >0)
  {
    const int base = tid * kPts;
#pragma unroll
    for (int m = 0; m < kPts; ++m) {
      int o = (int)(lds_key[base + m] & 8191u);
      px[m] = lds_pos[3 * o];
      py[m] = lds_pos[3 * o + 1];
      pz[m] = lds_pos[3 * o + 2];
      lo1_[m] = (u32)(8192 - o);
      dist_[m] = 1e10f;
      if (o == 0) { lds_c0[0] = px[m]; lds_c0[1] = py[m]; lds_c0[2] = pz[m]; }
    }
  }

  // ---- 6) sub-bucket bboxes + cached group keys ----
  float blx[kG], bhx[kG], bly[kG], bhy[kG], blz[kG], bhz[kG];
  float cgd[kG]; u32 cgl[kG], cgx[kG], cgy[kG], cgz[kG];
#pragma unroll
  for (int g = 0; g < kG; ++g) {
    float lx = 1e30f, hx = -1e30f, ly = 1e30f, hy = -1e30f, lz = 1e30f, hz = -1e30f;
    u32 lob = 0, wx = 0, wy = 0, wz = 0;
#pragma unroll
    for (int k = 0; k < kGp; ++k) {
      const int m = g * kGp + k;
      lx = fminf(lx, px[m]); hx = fmaxf(hx, px[m]);
      ly = fminf(ly, py[m]); hy = fmaxf(hy, py[m]);
      lz = fminf(lz, pz[m]); hz = fmaxf(hz, pz[m]);
      bool t = lo1_[m] > lob;           // all dists equal (1e10) -> max lo1 wins
      lob = t ? lo1_[m] : lob;
      wx = t ? __float_as_uint(px[m]) : wx;
      wy = t ? __float_as_uint(py[m]) : wy;
      wz = t ? __float_as_uint(pz[m]) : wz;
    }
    blx[g] = lx; bhx[g] = hx; bly[g] = ly; bhy[g] = hy; blz[g] = lz; bhz[g] = hz;
    cgd[g] = 1e10f; cgl[g] = lob; cgx[g] = wx; cgy[g] = wy; cgz[g] = wz;
  }

  // ---- 6b) wave-region bbox (uniform in all lanes) ----
  float wlx = fminf(blx[0], blx[1]), whx = fmaxf(bhx[0], bhx[1]);
  float wly = fminf(bly[0], bly[1]), why = fmaxf(bhy[0], bhy[1]);
  float wlz = fminf(blz[0], blz[1]), whz = fmaxf(bhz[0], bhz[1]);
#pragma unroll
  for (int m = 32; m >= 1; m >>= 1) {
    wlx = fminf(wlx, __shfl_xor(wlx, m, 64)); whx = fmaxf(whx, __shfl_xor(whx, m, 64));
    wly = fminf(wly, __shfl_xor(wly, m, 64)); why = fmaxf(why, __shfl_xor(why, m, 64));
    wlz = fminf(wlz, __shfl_xor(wlz, m, 64)); whz = fmaxf(whz, __shfl_xor(whz, m, 64));
  }

  // ---- 6c) initial cached wave key (lane 63 authoritative) ----
  float wkd; u32 wkl, wkx, wky, wkz;
  {
    float kd = cgd[0]; u32 kl = cgl[0], kx = cgx[0], ky = cgy[0], kz = cgz[0];
    keymax(kd, kl, kx, ky, kz, cgd[1], cgl[1], cgx[1], cgy[1], cgz[1]);
    DPP_REDUCE6();
    wkd = kd; wkl = kl; wkx = kx; wky = ky; wkz = kz;
  }
  __syncthreads();                      // lds_c0 visible

  // ---- 7) main FPS loop: one barrier per step ----
  float cx = lds_c0[0], cy = lds_c0[1], cz = lds_c0[2];
  float wall = 1e10f;                   // this wave's current max dist (uniform)
  int far = 0;
  for (int s = 0; ; ++s) {
    if (tid == 0) idx[s] = far;
    if (s == kN1 - 1) break;

    // wave-level gate: lower bound over the whole 1024-pt wave region
    float gxw = fmaxf(fmaxf(wlx - cx, cx - whx), 0.0f);
    float gyw = fmaxf(fmaxf(wly - cy, cy - why), 0.0f);
    float gzw = fmaxf(fmaxf(wlz - cz, cz - whz), 0.0f);
    float lb2w = gxw * gxw + gyw * gyw; lb2w = lb2w + gzw * gzw;

    if (!(lb2w * 0.999995f >= wall)) {  // uniform cond -> execz skip when pruned
#pragma unroll
      for (int g = 0; g < kG; ++g) {
        float gx = fmaxf(fmaxf(blx[g] - cx, cx - bhx[g]), 0.0f);
        float gy = fmaxf(fmaxf(bly[g] - cy, cy - bhy[g]), 0.0f);
        float gz = fmaxf(fmaxf(blz[g] - cz, cz - bhz[g]), 0.0f);
        float lb2 = gx * gx + gy * gy; lb2 = lb2 + gz * gz;
        if (!(lb2 * 0.999995f >= cgd[g])) {
          {
#pragma clang fp contract(off)
#pragma unroll
            for (int k = 0; k < kGp; ++k) {
              const int m = g * kGp + k;
              float dx = px[m] - cx;
              float dy = py[m] - cy;
              float dz = pz[m] - cz;
              float d = dx * dx + dy * dy;   // exact mul/add (XLA left fold)
              d = d + dz * dz;
              dist_[m] = fminf(dist_[m], d);
            }
          }
          float vb = dist_[g * kGp];
#pragma unroll
          for (int k = 1; k < kGp; ++k) vb = fmaxf(vb, dist_[g * kGp + k]);
          u32 lob = 0;
#pragma unroll
          for (int k = 0; k < kGp; ++k) {
            const int m = g * kGp + k;
            u32 c = (dist_[m] == vb) ? lo1_[m] : 0u;   // lo1 > 0 always
            lob = lob > c ? lob : c;
          }
          u32 wx = cgx[g], wy = cgy[g], wz = cgz[g];
#pragma unroll
          for (int k = 0; k < kGp; ++k) {
            const int m = g * kGp + k;
            bool t = (lo1_[m] == lob);                 // unique match
            wx = t ? __float_as_uint(px[m]) : wx;
            wy = t ? __float_as_uint(py[m]) : wy;
            wz = t ? __float_as_uint(pz[m]) : wz;
          }
          cgd[g] = vb; cgl[g] = lob; cgx[g] = wx; cgy[g] = wy; cgz[g] = wz;
        }
      }

      // wave reduce only when active
      float kd = cgd[0]; u32 kl = cgl[0], kx = cgx[0], ky = cgy[0], kz = cgz[0];
      keymax(kd, kl, kx, ky, kz, cgd[1], cgl[1], cgx[1], cgy[1], cgz[1]);
      DPP_REDUCE6();
      wkd = kd; wkl = kl; wkx = kx; wky = ky; wkz = kz;   // lanes 48-63 valid
    }

    if (lane == 63) {
      u32* slot = &wslot[s & 1][wave][0];
      slot[0] = __float_as_uint(wkd); slot[1] = wkl;
      slot[2] = wkx; slot[3] = wky; slot[4] = wkz;
    }
    __syncthreads();

    // cross-wave combine: 8 broadcast slot reads + static tree
    const u32 (*sl)[8] = wslot[s & 1];
    float sd[kW]; u32 sv[kW], sx[kW], sy[kW], sz[kW];
#pragma unroll
    for (int w = 0; w < kW; ++w) {
      uint4 q = *reinterpret_cast<const uint4*>(&sl[w][0]);
      sd[w] = __uint_as_float(q.x); sv[w] = q.y;
      sx[w] = q.z; sy[w] = q.w; sz[w] = sl[w][4];
    }
    wall = __uint_as_float(sl[wave][0]);   // own wave's current max (uniform)
#pragma unroll
    for (int st = 1; st < kW; st <<= 1)
#pragma unroll
      for (int w = 0; w < kW; w += 2 * st)
        keymax(sd[w], sv[w], sx[w], sy[w], sz[w],
               sd[w + st], sv[w + st], sx[w + st], sy[w + st], sz[w + st]);

    far = 8192 - (int)sv[0];
    cx = __uint_as_float(sx[0]);
    cy = __uint_as_float(sy[0]);
    cz = __uint_as_float(sz[0]);
  }
}

// ---------------------------------------------------------------------------
// Gather/assemble kernel (unchanged — proven bit-exact).
// fused_x: [B][14336][512] then fused_p: [B][14336][3].
// ---------------------------------------------------------------------------
constexpr int kXRows     = kB * kS;                    // 57344
constexpr int kXBlocks   = kXRows / 2;                 // 28672
constexpr int kPosElems  = kB * kS * 3;                // 172032
constexpr int kPosBlocks = kPosElems / 256;            // 672

__device__ __forceinline__ int src_row(int b, int r, const int* __restrict__ idx) {
  int s;
  if (r < kP)            s = r;
  else if (r < kP + kN1) s = idx[b * kN1 + (r - kP)];
  else                   s = idx[b * kN1 + (r - kP - kN1)];
  return b * kP + s;
}

__global__ __launch_bounds__(256)
void gather_kernel(const float* __restrict__ x, const float* __restrict__ pos,
                   const int* __restrict__ idx, float* __restrict__ out) {
  const int blk = blockIdx.x;
  if (blk < kXBlocks) {
    const int row  = blk * 2 + (threadIdx.x >> 7);    // 2 rows per block
    const int lane = threadIdx.x & 127;               // 128 float4 per row
    const int b = row / kS;
    const int r = row - b * kS;
    const int sr = src_row(b, r, idx);
    const float4* src4 = reinterpret_cast<const float4*>(x + (size_t)sr * kD);
    float4* dst4       = reinterpret_cast<float4*>(out + (size_t)row * kD);
    dst4[lane] = src4[lane];
  } else {
    const int e = (blk - kXBlocks) * 256 + threadIdx.x;   // [0, kPosElems)
    const int row = e / 3;
    const int c   = e - row * 3;
    const int b = row / kS;
    const int r = row - b * kS;
    const int sr = src_row(b, r, idx);
    float* outp = out + (size_t)kB * kS * kD;
    outp[e] = pos[sr * 3 + c];
  }
}

extern "C" void kernel_launch(void* const* d_in, const int* in_sizes, int n_in,
                              void* d_out, int out_size, void* d_ws, size_t ws_size,
                              hipStream_t stream) {
  const float* x   = (const float*)d_in[0];   // [B*P, D] f32
  const float* pos = (const float*)d_in[1];   // [B*P, 3] f32
  // d_in[2] = batch_idx (int64): sorted equal-sized batches -> layout implied
  int* idx = (int*)d_ws;                      // [B][kN1] int32 = 64 KiB

  fps_kernel<<<kB, kT, 0, stream>>>(pos, idx);
  gather_kernel<<<kXBlocks + kPosBlocks, 256, 0, stream>>>(x, pos, idx, (float*)d_out);
}

// Round 7
// 7460.421 us; speedup vs baseline: 1.0194x; 1.0194x over previous
//
#include <hip/hip_runtime.h>

// PyramidSampler: B=4 clouds of P=8192 pts, D=512 feats, scales (1.0, 0.5, 0.25).
// Scale 0.25's FPS indices are an exact prefix of scale 0.5's -> one 4096-step
// FPS per batch.
//
// R6: critical path = per-step fixed latency, not VALU (R5 cut VALU 20%, time
// flat). Two structural sinks removed:
//  (a) idx[s] global store inside the loop forced a vmcnt(0) drain at every
//      __syncthreads -> idx now buffered in the dead lds_key region, flushed
//      coalesced after the loop. Loop has ZERO vmem ops.
//  (b) cross-wave combine had all 512 threads read all 8 slots (128 LDS instrs
//      /step on one LDS pipe). Now lanes 0-7 read slot[lane] (16 instrs total),
//      3-DPP-stage reduce within lanes 0-7, readfirstlane -> SGPR far/cx/cy/cz.
//  (c) wall (wave's own max) via readlane(wkd,63) instead of an LDS re-read.
// Exact math preserved: no fma, (dx^2+dy^2)+dz^2 left fold, min-update, ties ->
// smallest original index (max lo1 = 8192-o), prune margins proven in R2-R5.

constexpr int kB   = 4;
constexpr int kP   = 8192;
constexpr int kD   = 512;
constexpr int kN1  = 4096;              // int(P*0.5)
constexpr int kN2  = 2048;              // int(P*0.25)
constexpr int kS   = kP + kN1 + kN2;    // 14336 rows per batch
constexpr int kT   = 512;               // 8 waves
constexpr int kW   = kT / 64;           // 8
constexpr int kPts = kP / kT;           // 16 points per thread
constexpr int kG   = 2;                 // sub-buckets per thread
constexpr int kGp  = kPts / kG;         // 8 points per sub-bucket

typedef unsigned long long u64;
typedef unsigned u32;

template <int CTRL>
__device__ __forceinline__ u32 dpp1(u32 v) {
  return (u32)__builtin_amdgcn_update_dpp((int)v, (int)v, CTRL, 0xF, 0xF, false);
}

// combined argmax key: (dist f32, lo1 u32 tie-break, coords as bits)
__device__ __forceinline__ void keymax(float& d, u32& l, u32& x, u32& y, u32& z,
                                       float od, u32 ol, u32 ox, u32 oy, u32 oz) {
  bool t = (od > d) || (od == d && ol > l);
  d = t ? od : d; l = t ? ol : l;
  x = t ? ox : x; y = t ? oy : y; z = t ? oz : z;
}

// one DPP butterfly/broadcast stage on the wave key (kd,kl,kx,ky,kz)
#define DPP_STAGE(CTRL)                                                     \
  {                                                                         \
    u32 pd = dpp1<CTRL>(__float_as_uint(kd));                               \
    u32 pl = dpp1<CTRL>(kl);                                                \
    u32 qx = dpp1<CTRL>(kx);                                                \
    u32 qy = dpp1<CTRL>(ky);                                                \
    u32 qz = dpp1<CTRL>(kz);                                                \
    keymax(kd, kl, kx, ky, kz, __uint_as_float(pd), pl, qx, qy, qz);        \
  }

#define DPP_REDUCE6()                                                       \
  DPP_STAGE(0xB1);  /* quad_perm xor1 */                                    \
  DPP_STAGE(0x4E);  /* quad_perm xor2 */                                    \
  DPP_STAGE(0x141); /* row_half_mirror */                                   \
  DPP_STAGE(0x140); /* row_mirror */                                        \
  DPP_STAGE(0x142); /* row_bcast15 */                                       \
  DPP_STAGE(0x143); /* row_bcast31 */

// 8-lane reduce (slots live in lanes 0..7; self-contained in lanes 0..7)
#define DPP_SLOT_STAGE(CTRL)                                                \
  {                                                                         \
    u32 pd = dpp1<CTRL>(__float_as_uint(sd));                               \
    u32 pl = dpp1<CTRL>(sv);                                                \
    u32 qx = dpp1<CTRL>(sx);                                                \
    u32 qy = dpp1<CTRL>(sy);                                                \
    u32 qz = dpp1<CTRL>(sz);                                                \
    keymax(sd, sv, sx, sy, sz, __uint_as_float(pd), pl, qx, qy, qz);        \
  }

__global__ __launch_bounds__(kT, 2)
void fps_kernel(const float* __restrict__ pos, int* __restrict__ idx_out) {
  const int b    = blockIdx.x;
  const int tid  = threadIdx.x;
  const int wave = tid >> 6;
  const int lane = tid & 63;
  const float* pb = pos + (size_t)b * kP * 3;
  int* idx = idx_out + b * kN1;

  __shared__ __attribute__((aligned(16))) float lds_pos[kP * 3];  // 96 KB (setup only)
  __shared__ __attribute__((aligned(16))) u32 lds_key[kP];        // 32 KB: sort keys, then idx buffer
  __shared__ float lds_bb[kW][6];
  __shared__ __attribute__((aligned(16))) u32 wslot[2][kW][8];    // [par][wave][d,lo1,x,y,z,..]
  __shared__ float lds_c0[3];

  // ---- 1) stage pos into LDS (orig order, coalesced float4) ----
  {
    const float4* src = reinterpret_cast<const float4*>(pb);
    float4* dst = reinterpret_cast<float4*>(lds_pos);
#pragma unroll
    for (int i = 0; i < (kP * 3 / 4) / kT; ++i)        // 12 iters
      dst[tid + i * kT] = src[tid + i * kT];
  }
  __syncthreads();

  // ---- 2) cloud bbox (block reduce; setup-only) ----
  float mn0 = 1e30f, mn1 = 1e30f, mn2 = 1e30f;
  float mx0 = -1e30f, mx1 = -1e30f, mx2 = -1e30f;
  for (int i = tid; i < kP; i += kT) {
    float x = lds_pos[3 * i], y = lds_pos[3 * i + 1], z = lds_pos[3 * i + 2];
    mn0 = fminf(mn0, x); mx0 = fmaxf(mx0, x);
    mn1 = fminf(mn1, y); mx1 = fmaxf(mx1, y);
    mn2 = fminf(mn2, z); mx2 = fmaxf(mx2, z);
  }
#pragma unroll
  for (int m = 32; m >= 1; m >>= 1) {
    mn0 = fminf(mn0, __shfl_xor(mn0, m, 64)); mx0 = fmaxf(mx0, __shfl_xor(mx0, m, 64));
    mn1 = fminf(mn1, __shfl_xor(mn1, m, 64)); mx1 = fmaxf(mx1, __shfl_xor(mx1, m, 64));
    mn2 = fminf(mn2, __shfl_xor(mn2, m, 64)); mx2 = fmaxf(mx2, __shfl_xor(mx2, m, 64));
  }
  if (lane == 0) {
    lds_bb[wave][0] = mn0; lds_bb[wave][1] = mn1; lds_bb[wave][2] = mn2;
    lds_bb[wave][3] = mx0; lds_bb[wave][4] = mx1; lds_bb[wave][5] = mx2;
  }
  __syncthreads();
#pragma unroll
  for (int w = 0; w < kW; ++w) {
    mn0 = fminf(mn0, lds_bb[w][0]); mn1 = fminf(mn1, lds_bb[w][1]); mn2 = fminf(mn2, lds_bb[w][2]);
    mx0 = fmaxf(mx0, lds_bb[w][3]); mx1 = fmaxf(mx1, lds_bb[w][4]); mx2 = fmaxf(mx2, lds_bb[w][5]);
  }

  // ---- 3) Morton keys: 18-bit code << 13 | orig idx ----
  {
    const float i0 = 63.0f / fmaxf(mx0 - mn0, 1e-20f);
    const float i1 = 63.0f / fmaxf(mx1 - mn1, 1e-20f);
    const float i2 = 63.0f / fmaxf(mx2 - mn2, 1e-20f);
    for (int i = tid; i < kP; i += kT) {
      int qx = (int)((lds_pos[3 * i]     - mn0) * i0);
      int qy = (int)((lds_pos[3 * i + 1] - mn1) * i1);
      int qz = (int)((lds_pos[3 * i + 2] - mn2) * i2);
      qx = min(max(qx, 0), 63); qy = min(max(qy, 0), 63); qz = min(max(qz, 0), 63);
      u32 code = 0;
#pragma unroll
      for (int t = 0; t < 6; ++t)
        code |= (((u32)(qx >> t) & 1u) << (3 * t)) |
                (((u32)(qy >> t) & 1u) << (3 * t + 1)) |
                (((u32)(qz >> t) & 1u) << (3 * t + 2));
      lds_key[i] = (code << 13) | (u32)i;
    }
  }
  __syncthreads();

  // ---- 4) bitonic sort of 8192 u32 keys (unique: idx in low bits) ----
  for (int kk = 2; kk <= kP; kk <<= 1) {
    for (int j = kk >> 1; j > 0; j >>= 1) {
      const int mask = j - 1;
#pragma unroll
      for (int it = 0; it < (kP / 2) / kT; ++it) {     // 8 iters
        int i = tid + it * kT;
        int a = ((i & ~mask) << 1) | (i & mask);
        int c = a | j;
        u32 x = lds_key[a], y = lds_key[c];
        bool up = ((a & kk) == 0);
        if ((x > y) == up) { lds_key[a] = y; lds_key[c] = x; }
      }
      __syncthreads();
    }
  }

  // ---- 5) gather 16 pts/thread into registers (sorted order) ----
  float px[kPts], py[kPts], pz[kPts], dist_[kPts];
  u32 lo1_[kPts];                       // 8192 - orig_idx (unique, >0)
  {
    const int base = tid * kPts;
#pragma unroll
    for (int m = 0; m < kPts; ++m) {
      int o = (int)(lds_key[base + m] & 8191u);
      px[m] = lds_pos[3 * o];
      py[m] = lds_pos[3 * o + 1];
      pz[m] = lds_pos[3 * o + 2];
      lo1_[m] = (u32)(8192 - o);
      dist_[m] = 1e10f;
      if (o == 0) { lds_c0[0] = px[m]; lds_c0[1] = py[m]; lds_c0[2] = pz[m]; }
    }
  }

  // ---- 6) sub-bucket bboxes + cached group keys ----
  float blx[kG], bhx[kG], bly[kG], bhy[kG], blz[kG], bhz[kG];
  float cgd[kG]; u32 cgl[kG], cgx[kG], cgy[kG], cgz[kG];
#pragma unroll
  for (int g = 0; g < kG; ++g) {
    float lx = 1e30f, hx = -1e30f, ly = 1e30f, hy = -1e30f, lz = 1e30f, hz = -1e30f;
    u32 lob = 0, wx = 0, wy = 0, wz = 0;
#pragma unroll
    for (int k = 0; k < kGp; ++k) {
      const int m = g * kGp + k;
      lx = fminf(lx, px[m]); hx = fmaxf(hx, px[m]);
      ly = fminf(ly, py[m]); hy = fmaxf(hy, py[m]);
      lz = fminf(lz, pz[m]); hz = fmaxf(hz, pz[m]);
      bool t = lo1_[m] > lob;           // all dists equal (1e10) -> max lo1 wins
      lob = t ? lo1_[m] : lob;
      wx = t ? __float_as_uint(px[m]) : wx;
      wy = t ? __float_as_uint(py[m]) : wy;
      wz = t ? __float_as_uint(pz[m]) : wz;
    }
    blx[g] = lx; bhx[g] = hx; bly[g] = ly; bhy[g] = hy; blz[g] = lz; bhz[g] = hz;
    cgd[g] = 1e10f; cgl[g] = lob; cgx[g] = wx; cgy[g] = wy; cgz[g] = wz;
  }

  // ---- 6b) wave-region bbox (uniform in all lanes) ----
  float wlx = fminf(blx[0], blx[1]), whx = fmaxf(bhx[0], bhx[1]);
  float wly = fminf(bly[0], bly[1]), why = fmaxf(bhy[0], bhy[1]);
  float wlz = fminf(blz[0], blz[1]), whz = fmaxf(bhz[0], bhz[1]);
#pragma unroll
  for (int m = 32; m >= 1; m >>= 1) {
    wlx = fminf(wlx, __shfl_xor(wlx, m, 64)); whx = fmaxf(whx, __shfl_xor(whx, m, 64));
    wly = fminf(wly, __shfl_xor(wly, m, 64)); why = fmaxf(why, __shfl_xor(why, m, 64));
    wlz = fminf(wlz, __shfl_xor(wlz, m, 64)); whz = fmaxf(whz, __shfl_xor(whz, m, 64));
  }

  // ---- 6c) initial cached wave key (lanes 48-63 authoritative) ----
  float wkd; u32 wkl, wkx, wky, wkz;
  {
    float kd = cgd[0]; u32 kl = cgl[0], kx = cgx[0], ky = cgy[0], kz = cgz[0];
    keymax(kd, kl, kx, ky, kz, cgd[1], cgl[1], cgx[1], cgy[1], cgz[1]);
    DPP_REDUCE6();
    wkd = kd; wkl = kl; wkx = kx; wky = ky; wkz = kz;
  }
  __syncthreads();                      // lds_c0 visible; lds_key reads all done

  // ---- 7) main FPS loop: one barrier per step, ZERO vmem ops ----
  float cx = lds_c0[0], cy = lds_c0[1], cz = lds_c0[2];
  float wall = 1e10f;                   // this wave's current max dist (uniform)
  int far = 0;
  for (int s = 0; ; ++s) {
    if (tid == 0) lds_key[s] = (u32)far;          // LDS buffer, not global
    if (s == kN1 - 1) break;

    // wave-level gate: lower bound over the whole 1024-pt wave region
    float gxw = fmaxf(fmaxf(wlx - cx, cx - whx), 0.0f);
    float gyw = fmaxf(fmaxf(wly - cy, cy - why), 0.0f);
    float gzw = fmaxf(fmaxf(wlz - cz, cz - whz), 0.0f);
    float lb2w = gxw * gxw + gyw * gyw; lb2w = lb2w + gzw * gzw;

    if (!(lb2w * 0.999995f >= wall)) {  // uniform cond -> execz skip when pruned
#pragma unroll
      for (int g = 0; g < kG; ++g) {
        float gx = fmaxf(fmaxf(blx[g] - cx, cx - bhx[g]), 0.0f);
        float gy = fmaxf(fmaxf(bly[g] - cy, cy - bhy[g]), 0.0f);
        float gz = fmaxf(fmaxf(blz[g] - cz, cz - bhz[g]), 0.0f);
        float lb2 = gx * gx + gy * gy; lb2 = lb2 + gz * gz;
        if (!(lb2 * 0.999995f >= cgd[g])) {
          {
#pragma clang fp contract(off)
#pragma unroll
            for (int k = 0; k < kGp; ++k) {
              const int m = g * kGp + k;
              float dx = px[m] - cx;
              float dy = py[m] - cy;
              float dz = pz[m] - cz;
              float d = dx * dx + dy * dy;   // exact mul/add (XLA left fold)
              d = d + dz * dz;
              dist_[m] = fminf(dist_[m], d);
            }
          }
          float vb = dist_[g * kGp];
#pragma unroll
          for (int k = 1; k < kGp; ++k) vb = fmaxf(vb, dist_[g * kGp + k]);
          u32 lob = 0;
#pragma unroll
          for (int k = 0; k < kGp; ++k) {
            const int m = g * kGp + k;
            u32 c = (dist_[m] == vb) ? lo1_[m] : 0u;   // lo1 > 0 always
            lob = lob > c ? lob : c;
          }
          u32 wx = cgx[g], wy = cgy[g], wz = cgz[g];
#pragma unroll
          for (int k = 0; k < kGp; ++k) {
            const int m = g * kGp + k;
            bool t = (lo1_[m] == lob);                 // unique match
            wx = t ? __float_as_uint(px[m]) : wx;
            wy = t ? __float_as_uint(py[m]) : wy;
            wz = t ? __float_as_uint(pz[m]) : wz;
          }
          cgd[g] = vb; cgl[g] = lob; cgx[g] = wx; cgy[g] = wy; cgz[g] = wz;
        }
      }

      // wave reduce only when active
      float kd = cgd[0]; u32 kl = cgl[0], kx = cgx[0], ky = cgy[0], kz = cgz[0];
      keymax(kd, kl, kx, ky, kz, cgd[1], cgl[1], cgx[1], cgy[1], cgz[1]);
      DPP_REDUCE6();
      wkd = kd; wkl = kl; wkx = kx; wky = ky; wkz = kz;   // lanes 48-63 valid
      wall = __uint_as_float(__builtin_amdgcn_readlane(__float_as_uint(wkd), 63));
    }

    if (lane == 63) {
      u32* slot = &wslot[s & 1][wave][0];
      slot[0] = __float_as_uint(wkd); slot[1] = wkl;
      slot[2] = wkx; slot[3] = wky; slot[4] = wkz;
    }
    __syncthreads();

    // cross-wave combine: lanes 0-7 read slot[lane], 3-stage DPP reduce
    // (self-contained within lanes 0-7), winner -> SGPRs via readfirstlane.
    float sd = 0.0f; u32 sv = 0, sx = 0, sy = 0, sz = 0;
    if (lane < kW) {
      const u32* slot = &wslot[s & 1][lane][0];
      uint4 q = *reinterpret_cast<const uint4*>(slot);
      sd = __uint_as_float(q.x); sv = q.y;
      sx = q.z; sy = q.w; sz = slot[4];
      DPP_SLOT_STAGE(0xB1);   // xor1 within quad
      DPP_SLOT_STAGE(0x4E);   // xor2 within quad
      DPP_SLOT_STAGE(0x141);  // row_half_mirror: combine quads 0 and 1
    }
    far = 8192 - (int)__builtin_amdgcn_readfirstlane((int)sv);
    cx = __uint_as_float(__builtin_amdgcn_readfirstlane((int)sx));
    cy = __uint_as_float(__builtin_amdgcn_readfirstlane((int)sy));
    cz = __uint_as_float(__builtin_amdgcn_readfirstlane((int)sz));
  }

  // ---- 8) flush idx buffer to global (coalesced) ----
  __syncthreads();
  {
    const uint4* src = reinterpret_cast<const uint4*>(lds_key);
    uint4* dst = reinterpret_cast<uint4*>(idx);
#pragma unroll
    for (int i = 0; i < (kN1 / 4) / kT; ++i)           // 2 iters
      dst[tid + i * kT] = src[tid + i * kT];
  }
}

// ---------------------------------------------------------------------------
// Gather/assemble kernel (unchanged — proven bit-exact).
// fused_x: [B][14336][512] then fused_p: [B][14336][3].
// ---------------------------------------------------------------------------
constexpr int kXRows     = kB * kS;                    // 57344
constexpr int kXBlocks   = kXRows / 2;                 // 28672
constexpr int kPosElems  = kB * kS * 3;                // 172032
constexpr int kPosBlocks = kPosElems / 256;            // 672

__device__ __forceinline__ int src_row(int b, int r, const int* __restrict__ idx) {
  int s;
  if (r < kP)            s = r;
  else if (r < kP + kN1) s = idx[b * kN1 + (r - kP)];
  else                   s = idx[b * kN1 + (r - kP - kN1)];
  return b * kP + s;
}

__global__ __launch_bounds__(256)
void gather_kernel(const float* __restrict__ x, const float* __restrict__ pos,
                   const int* __restrict__ idx, float* __restrict__ out) {
  const int blk = blockIdx.x;
  if (blk < kXBlocks) {
    const int row  = blk * 2 + (threadIdx.x >> 7);    // 2 rows per block
    const int lane = threadIdx.x & 127;               // 128 float4 per row
    const int b = row / kS;
    const int r = row - b * kS;
    const int sr = src_row(b, r, idx);
    const float4* src4 = reinterpret_cast<const float4*>(x + (size_t)sr * kD);
    float4* dst4       = reinterpret_cast<float4*>(out + (size_t)row * kD);
    dst4[lane] = src4[lane];
  } else {
    const int e = (blk - kXBlocks) * 256 + threadIdx.x;   // [0, kPosElems)
    const int row = e / 3;
    const int c   = e - row * 3;
    const int b = row / kS;
    const int r = row - b * kS;
    const int sr = src_row(b, r, idx);
    float* outp = out + (size_t)kB * kS * kD;
    outp[e] = pos[sr * 3 + c];
  }
}

extern "C" void kernel_launch(void* const* d_in, const int* in_sizes, int n_in,
                              void* d_out, int out_size, void* d_ws, size_t ws_size,
                              hipStream_t stream) {
  const float* x   = (const float*)d_in[0];   // [B*P, D] f32
  const float* pos = (const float*)d_in[1];   // [B*P, 3] f32
  // d_in[2] = batch_idx (int64): sorted equal-sized batches -> layout implied
  int* idx = (int*)d_ws;                      // [B][kN1] int32 = 64 KiB

  fps_kernel<<<kB, kT, 0, stream>>>(pos, idx);
  gather_kernel<<<kXBlocks + kPosBlocks, 256, 0, stream>>>(x, pos, idx, (float*)d_out);
}